// Round 1
// baseline (872.649 us; speedup 1.0000x reference)
//
#include <hip/hip_runtime.h>
#include <math.h>

#define IN_DIM 256
#define HD 128
#define OUT_DIM 40

// ---------------- preprocessing kernels ----------------

__global__ __launch_bounds__(256) void k_init(int* deg, float* muacc, int N) {
    int i = blockIdx.x * 256 + threadIdx.x;
    if (i < N) deg[i] = 1;                 // self-loop
    if (blockIdx.x == 0 && threadIdx.x < 256) muacc[threadIdx.x] = 0.f;
}

__global__ __launch_bounds__(256) void k_colsum(const float* __restrict__ x, int N,
                                                float* __restrict__ muacc) {
    int c = threadIdx.x;                   // column 0..255
    int r0 = blockIdx.x * 128;
    int r1 = min(r0 + 128, N);
    float s = 0.f;
    for (int r = r0; r < r1; ++r) s += x[(size_t)r * IN_DIM + c];
    atomicAdd(&muacc[c], s);
}

__global__ __launch_bounds__(256) void k_deg(const int* __restrict__ ei, int E, int* deg) {
    int e = blockIdx.x * 256 + threadIdx.x;
    if (e >= E) return;
    atomicAdd(&deg[ei[E + e]], 1);         // dst = ei[1][e]
}

__global__ __launch_bounds__(256) void k_bp(const int* __restrict__ deg, int N, int* bp) {
    __shared__ int sm[256];
    int i = blockIdx.x * 256 + threadIdx.x;
    sm[threadIdx.x] = (i < N) ? (deg[i] - 1) : 0;
    __syncthreads();
    for (int off = 128; off; off >>= 1) {
        if (threadIdx.x < off) sm[threadIdx.x] += sm[threadIdx.x + off];
        __syncthreads();
    }
    if (threadIdx.x == 0) bp[blockIdx.x] = sm[0];
}

__global__ __launch_bounds__(512) void k_scanbp(const int* __restrict__ bp, int NB, int* bps) {
    __shared__ int sm[512];
    int t = threadIdx.x;
    int v = (t < NB) ? bp[t] : 0;
    sm[t] = v;
    __syncthreads();
    for (int off = 1; off < 512; off <<= 1) {
        int add = (t >= off) ? sm[t - off] : 0;
        __syncthreads();
        sm[t] += add;
        __syncthreads();
    }
    if (t < NB) bps[t] = sm[t] - v;        // exclusive
}

__global__ __launch_bounds__(256) void k_rowptr(const int* __restrict__ deg,
                                                const int* __restrict__ bps, int N, int E,
                                                int* row_ptr, int* cursor, float* dinv) {
    __shared__ int wsum[4];
    int t = threadIdx.x, lane = t & 63, w = t >> 6;
    int i = blockIdx.x * 256 + t;
    int c = (i < N) ? (deg[i] - 1) : 0;
    int v = c;
    #pragma unroll
    for (int off = 1; off < 64; off <<= 1) {
        int n = __shfl_up(v, off);
        if (lane >= off) v += n;
    }
    if (lane == 63) wsum[w] = v;
    __syncthreads();
    int wo = 0;
    for (int k = 0; k < w; ++k) wo += wsum[k];
    int excl = bps[blockIdx.x] + wo + v - c;
    if (i < N) {
        row_ptr[i] = excl;
        cursor[i] = excl;
        dinv[i] = (float)(1.0 / sqrt((double)deg[i]));
    }
    if (blockIdx.x == 0 && t == 0) row_ptr[N] = E;
}

__global__ __launch_bounds__(256) void k_scatter(const int* __restrict__ ei, int E,
                                                 const float* __restrict__ dinv, int* cursor,
                                                 int* cs_src, float* cs_norm) {
    int e = blockIdx.x * 256 + threadIdx.x;
    if (e >= E) return;
    int s = ei[e];
    int d = ei[E + e];
    int pos = atomicAdd(&cursor[d], 1);
    cs_src[pos] = s;
    cs_norm[pos] = dinv[s] * dinv[d];
}

// pack weight sign bits + 2*mean|W| per column.
// K=256 convention: word q bit l <-> row (l + 64q). K=128: word q bit l <-> row (2l + q).
__global__ __launch_bounds__(256) void k_wprep(const float* __restrict__ W0,
                                               const float* __restrict__ W1,
                                               const float* __restrict__ W2,
                                               unsigned long long* W0p,
                                               unsigned long long* W1p,
                                               unsigned long long* W2p,
                                               float* aS0, float* aS1, float* aS2) {
    int t = threadIdx.x, lane = t & 63, w = t >> 6;
    int b = blockIdx.x;
    if (b < 32) {                                  // W0: [256,128]
        int j = b * 4 + w;
        float asum = 0.f;
        unsigned long long words[4];
        #pragma unroll
        for (int q = 0; q < 4; ++q) {
            float v = W0[(size_t)(lane + 64 * q) * HD + j];
            asum += fabsf(v);
            words[q] = __ballot(v < 0.f);
        }
        #pragma unroll
        for (int off = 32; off; off >>= 1) asum += __shfl_xor(asum, off);
        if (lane == 0) {
            aS0[j] = 2.f * asum / 256.f;
            #pragma unroll
            for (int q = 0; q < 4; ++q) W0p[j * 4 + q] = words[q];
        }
    } else if (b < 64) {                           // W1: [128,128]
        int j = (b - 32) * 4 + w;
        float asum = 0.f;
        unsigned long long words[2];
        #pragma unroll
        for (int q = 0; q < 2; ++q) {
            float v = W1[(size_t)(2 * lane + q) * HD + j];
            asum += fabsf(v);
            words[q] = __ballot(v < 0.f);
        }
        #pragma unroll
        for (int off = 32; off; off >>= 1) asum += __shfl_xor(asum, off);
        if (lane == 0) {
            aS1[j] = 2.f * asum / 128.f;
            W1p[j * 2 + 0] = words[0];
            W1p[j * 2 + 1] = words[1];
        }
    } else {                                       // W2: [128,40]
        int j = (b - 64) * 4 + w;
        if (j < OUT_DIM) {
            float asum = 0.f;
            unsigned long long words[2];
            #pragma unroll
            for (int q = 0; q < 2; ++q) {
                float v = W2[(size_t)(2 * lane + q) * OUT_DIM + j];
                asum += fabsf(v);
                words[q] = __ballot(v < 0.f);
            }
            #pragma unroll
            for (int off = 32; off; off >>= 1) asum += __shfl_xor(asum, off);
            if (lane == 0) {
                aS2[j] = 2.f * asum / 128.f;
                W2p[j * 2 + 0] = words[0];
                W2p[j * 2 + 1] = words[1];
            }
        }
    }
}

// ---------------- layer 0: sign(x-mu) + popcount matmul -> S0 (int8 = S/2) ----------------
__global__ __launch_bounds__(256) void k_x_mm0(const float* __restrict__ x,
                                               const float* __restrict__ muacc, float inv_n,
                                               const unsigned long long* __restrict__ W0p,
                                               signed char* __restrict__ S0, int N) {
    __shared__ unsigned long long w0s[128 * 4];
    int tid = threadIdx.x;
    w0s[tid] = W0p[tid];
    w0s[tid + 256] = W0p[tid + 256];
    __syncthreads();
    int lane = tid & 63;
    int row = blockIdx.x * 4 + (tid >> 6);
    if (row >= N) return;
    const float* xr = x + (size_t)row * IN_DIM;
    unsigned long long xw[4];
    #pragma unroll
    for (int w = 0; w < 4; ++w) {
        int c = lane + 64 * w;
        float v = xr[c] - muacc[c] * inv_n;
        xw[w] = __ballot(v < 0.f);
    }
    unsigned int pack = 0;
    #pragma unroll
    for (int t2 = 0; t2 < 2; ++t2) {
        int j = 2 * lane + t2;
        const unsigned long long* wc = &w0s[j * 4];
        int dd = __popcll(xw[0] ^ wc[0]) + __popcll(xw[1] ^ wc[1]) +
                 __popcll(xw[2] ^ wc[2]) + __popcll(xw[3] ^ wc[3]);
        int S = IN_DIM - 2 * dd;   // even, [-256,256]
        int s8 = S >> 1;           // [-128,128]
        if (s8 > 127) s8 = 127;    // only |S|=256 clamps (prob ~0)
        pack |= ((unsigned)(unsigned char)(signed char)s8) << (8 * t2);
    }
    *(unsigned short*)(S0 + (size_t)row * HD + 2 * lane) = (unsigned short)pack;
}

// ---------------- agg + binarize + fused next popcount matmul ----------------
template <int OUTC>
__global__ __launch_bounds__(256) void k_agg_mm(const signed char* __restrict__ Sin,  // [N][128]
                                                const int* __restrict__ row_ptr,
                                                const int* __restrict__ cs_src,
                                                const float* __restrict__ cs_norm,
                                                const float* __restrict__ dinv,
                                                const float* __restrict__ alphaS,
                                                const float* __restrict__ bias,
                                                const unsigned long long* __restrict__ Wnp,
                                                signed char* __restrict__ Sout, int N) {
    __shared__ unsigned long long wsm[OUTC * 2];
    int tid = threadIdx.x;
    for (int i = tid; i < OUTC * 2; i += 256) wsm[i] = Wnp[i];
    __syncthreads();
    int lane = tid & 63;
    int d = blockIdx.x * 4 + (tid >> 6);
    if (d >= N) return;
    float acc0 = 0.f, acc1 = 0.f;
    {   // self loop
        float dv = dinv[d];
        float nrm = dv * dv;
        unsigned short u = *(const unsigned short*)(Sin + (size_t)d * HD + 2 * lane);
        acc0 += nrm * (float)(signed char)(u & 0xff);
        acc1 += nrm * (float)(signed char)(u >> 8);
    }
    int e0 = row_ptr[d], e1 = row_ptr[d + 1];
    for (int e = e0; e < e1; ++e) {
        int s = cs_src[e];
        float nrm = cs_norm[e];
        unsigned short u = *(const unsigned short*)(Sin + (size_t)s * HD + 2 * lane);
        acc0 += nrm * (float)(signed char)(u & 0xff);
        acc1 += nrm * (float)(signed char)(u >> 8);
    }
    int j0 = 2 * lane;
    float v0 = alphaS[j0] * acc0 + bias[j0];
    float v1 = alphaS[j0 + 1] * acc1 + bias[j0 + 1];
    unsigned long long w0 = __ballot(v0 < 0.f);   // bit l <-> feature 2l
    unsigned long long w1 = __ballot(v1 < 0.f);   // bit l <-> feature 2l+1
    if (OUTC == 128) {
        unsigned int pack = 0;
        #pragma unroll
        for (int t2 = 0; t2 < 2; ++t2) {
            int j = 2 * lane + t2;
            int dd = __popcll(w0 ^ wsm[j * 2]) + __popcll(w1 ^ wsm[j * 2 + 1]);
            int S = HD - 2 * dd;  // even, [-128,128]
            pack |= ((unsigned)(unsigned char)(signed char)(S >> 1)) << (8 * t2);
        }
        *(unsigned short*)(Sout + (size_t)d * HD + 2 * lane) = (unsigned short)pack;
    } else {
        if (lane < OUTC) {
            int dd = __popcll(w0 ^ wsm[lane * 2]) + __popcll(w1 ^ wsm[lane * 2 + 1]);
            int S = HD - 2 * dd;
            Sout[(size_t)d * OUTC + lane] = (signed char)(S >> 1);
        }
    }
}

// ---------------- final agg + log_softmax ----------------
__global__ __launch_bounds__(256) void k_agg_out(const signed char* __restrict__ S2,  // [N][40]
                                                 const int* __restrict__ row_ptr,
                                                 const int* __restrict__ cs_src,
                                                 const float* __restrict__ cs_norm,
                                                 const float* __restrict__ dinv,
                                                 const float* __restrict__ alphaS2,
                                                 const float* __restrict__ b2,
                                                 float* __restrict__ out, int N) {
    int tid = threadIdx.x, lane = tid & 63;
    int d = blockIdx.x * 4 + (tid >> 6);
    if (d >= N) return;
    bool act = lane < OUT_DIM;
    float acc = 0.f;
    {
        float dv = dinv[d];
        float nrm = dv * dv;
        if (act) acc += nrm * (float)S2[(size_t)d * OUT_DIM + lane];
    }
    int e0 = row_ptr[d], e1 = row_ptr[d + 1];
    for (int e = e0; e < e1; ++e) {
        int s = cs_src[e];
        float nrm = cs_norm[e];
        if (act) acc += nrm * (float)S2[(size_t)s * OUT_DIM + lane];
    }
    float h = act ? (alphaS2[lane] * acc + b2[lane]) : -INFINITY;
    float m = h;
    #pragma unroll
    for (int off = 32; off; off >>= 1) m = fmaxf(m, __shfl_xor(m, off));
    float ex = act ? expf(h - m) : 0.f;
    float ssum = ex;
    #pragma unroll
    for (int off = 32; off; off >>= 1) ssum += __shfl_xor(ssum, off);
    if (act) out[(size_t)d * OUT_DIM + lane] = h - m - logf(ssum);
}

// ---------------- launcher ----------------
extern "C" void kernel_launch(void* const* d_in, const int* in_sizes, int n_in,
                              void* d_out, int out_size, void* d_ws, size_t ws_size,
                              hipStream_t stream) {
    const float* x  = (const float*)d_in[0];
    const int*   ei = (const int*)d_in[1];
    const float* W0 = (const float*)d_in[2];
    const float* b0 = (const float*)d_in[3];
    const float* W1 = (const float*)d_in[4];
    const float* b1 = (const float*)d_in[5];
    const float* W2 = (const float*)d_in[6];
    const float* b2 = (const float*)d_in[7];
    float* out = (float*)d_out;

    int N = in_sizes[0] / IN_DIM;
    int E = in_sizes[1] / 2;

    char* ws = (char*)d_ws;
    size_t off = 0;
    auto alloc = [&](size_t bytes) -> void* {
        off = (off + 255) & ~(size_t)255;
        void* p = (void*)(ws + off);
        off += bytes;
        return p;
    };
    float* muacc  = (float*)alloc(256 * 4);
    int*   deg    = (int*)alloc((size_t)N * 4);
    float* dinv   = (float*)alloc((size_t)N * 4);
    int*   rowp   = (int*)alloc(((size_t)N + 1) * 4);
    int*   cursor = (int*)alloc((size_t)N * 4);
    int*   bp     = (int*)alloc(512 * 4);
    int*   bps    = (int*)alloc(512 * 4);
    int*   cs_src = (int*)alloc((size_t)E * 4);
    float* cs_nrm = (float*)alloc((size_t)E * 4);
    signed char* S0 = (signed char*)alloc((size_t)N * HD);
    signed char* S1 = (signed char*)alloc((size_t)N * HD);
    signed char* S2 = (signed char*)alloc((size_t)N * OUT_DIM);
    unsigned long long* W0p = (unsigned long long*)alloc(128 * 4 * 8);
    unsigned long long* W1p = (unsigned long long*)alloc(128 * 2 * 8);
    unsigned long long* W2p = (unsigned long long*)alloc(40 * 2 * 8);
    float* aS0 = (float*)alloc(128 * 4);
    float* aS1 = (float*)alloc(128 * 4);
    float* aS2 = (float*)alloc(40 * 4);

    int nb256 = (N + 255) / 256;
    int ebl = (E + 255) / 256;
    float inv_n = 1.0f / (float)N;

    k_init<<<dim3(nb256), dim3(256), 0, stream>>>(deg, muacc, N);
    k_colsum<<<dim3((N + 127) / 128), dim3(256), 0, stream>>>(x, N, muacc);
    k_deg<<<dim3(ebl), dim3(256), 0, stream>>>(ei, E, deg);
    k_bp<<<dim3(nb256), dim3(256), 0, stream>>>(deg, N, bp);
    k_scanbp<<<dim3(1), dim3(512), 0, stream>>>(bp, nb256, bps);
    k_rowptr<<<dim3(nb256), dim3(256), 0, stream>>>(deg, bps, N, E, rowp, cursor, dinv);
    k_scatter<<<dim3(ebl), dim3(256), 0, stream>>>(ei, E, dinv, cursor, cs_src, cs_nrm);
    k_wprep<<<dim3(74), dim3(256), 0, stream>>>(W0, W1, W2, W0p, W1p, W2p, aS0, aS1, aS2);

    int nb4 = (N + 3) / 4;
    k_x_mm0<<<dim3(nb4), dim3(256), 0, stream>>>(x, muacc, inv_n, W0p, S0, N);
    k_agg_mm<128><<<dim3(nb4), dim3(256), 0, stream>>>(S0, rowp, cs_src, cs_nrm, dinv,
                                                       aS0, b0, W1p, S1, N);
    k_agg_mm<40><<<dim3(nb4), dim3(256), 0, stream>>>(S1, rowp, cs_src, cs_nrm, dinv,
                                                      aS1, b1, W2p, S2, N);
    k_agg_out<<<dim3(nb4), dim3(256), 0, stream>>>(S2, rowp, cs_src, cs_nrm, dinv,
                                                   aS2, b2, out, N);
    (void)out_size; (void)ws_size; (void)n_in;
}

// Round 3
// 622.925 us; speedup vs baseline: 1.4009x; 1.4009x over previous
//
#include <hip/hip_runtime.h>
#include <math.h>

#define IN_DIM 256
#define HD 128
#define OUT_DIM 40
#define S2_STRIDE 64

// ---------------- preprocessing kernels ----------------

__global__ __launch_bounds__(256) void k_init(int* deg, float* muacc, int N) {
    int i = blockIdx.x * 256 + threadIdx.x;
    if (i < N) deg[i] = 1;                 // self-loop
    if (blockIdx.x == 0 && threadIdx.x < 256) muacc[threadIdx.x] = 0.f;
}

__global__ __launch_bounds__(256) void k_colsum(const float* __restrict__ x, int N,
                                                float* __restrict__ muacc) {
    int c = threadIdx.x;                   // column 0..255
    int r0 = blockIdx.x * 128;
    int r1 = min(r0 + 128, N);
    float s = 0.f;
    for (int r = r0; r < r1; ++r) s += x[(size_t)r * IN_DIM + c];
    atomicAdd(&muacc[c], s);
}

__global__ __launch_bounds__(256) void k_deg(const int* __restrict__ ei, int E, int* deg) {
    int e = blockIdx.x * 256 + threadIdx.x;
    if (e >= E) return;
    atomicAdd(&deg[ei[E + e]], 1);         // dst = ei[1][e]
}

__global__ __launch_bounds__(256) void k_bp(const int* __restrict__ deg, int N, int* bp) {
    __shared__ int sm[256];
    int i = blockIdx.x * 256 + threadIdx.x;
    sm[threadIdx.x] = (i < N) ? (deg[i] - 1) : 0;
    __syncthreads();
    for (int off = 128; off; off >>= 1) {
        if (threadIdx.x < off) sm[threadIdx.x] += sm[threadIdx.x + off];
        __syncthreads();
    }
    if (threadIdx.x == 0) bp[blockIdx.x] = sm[0];
}

__global__ __launch_bounds__(512) void k_scanbp(const int* __restrict__ bp, int NB, int* bps) {
    __shared__ int sm[512];
    int t = threadIdx.x;
    int v = (t < NB) ? bp[t] : 0;
    sm[t] = v;
    __syncthreads();
    for (int off = 1; off < 512; off <<= 1) {
        int add = (t >= off) ? sm[t - off] : 0;
        __syncthreads();
        sm[t] += add;
        __syncthreads();
    }
    if (t < NB) bps[t] = sm[t] - v;        // exclusive
}

__global__ __launch_bounds__(256) void k_rowptr(const int* __restrict__ deg,
                                                const int* __restrict__ bps, int N, int E,
                                                int* row_ptr, int* cursor, float* dinv) {
    __shared__ int wsum[4];
    int t = threadIdx.x, lane = t & 63, w = t >> 6;
    int i = blockIdx.x * 256 + t;
    int c = (i < N) ? (deg[i] - 1) : 0;
    int v = c;
    #pragma unroll
    for (int off = 1; off < 64; off <<= 1) {
        int n = __shfl_up(v, off);
        if (lane >= off) v += n;
    }
    if (lane == 63) wsum[w] = v;
    __syncthreads();
    int wo = 0;
    for (int k = 0; k < w; ++k) wo += wsum[k];
    int excl = bps[blockIdx.x] + wo + v - c;
    if (i < N) {
        row_ptr[i] = excl;
        cursor[i] = excl;
        dinv[i] = (float)(1.0 / sqrt((double)deg[i]));
    }
    if (blockIdx.x == 0 && t == 0) row_ptr[N] = E;
}

// packed edge record: low 32 = src, high 32 = bitcast(norm)
__global__ __launch_bounds__(256) void k_scatter(const int* __restrict__ ei, int E,
                                                 const float* __restrict__ dinv, int* cursor,
                                                 long long* cs) {
    int e = blockIdx.x * 256 + threadIdx.x;
    if (e >= E) return;
    int s = ei[e];
    int d = ei[E + e];
    int pos = atomicAdd(&cursor[d], 1);
    float nrm = dinv[s] * dinv[d];
    long long v = (long long)(unsigned int)s |
                  ((long long)(unsigned int)__float_as_int(nrm) << 32);
    cs[pos] = v;
}

// pack weight sign bits + 2*mean|W| per column.
// W0 (K=256): word q bit l <-> row (l + 64q)                  [k_x_mm0 convention]
// W1/W2 (K=128): word q bit (fl + 16*kk) <-> row fl*8 + 4q + kk, fl=0..15, kk=0..3
__global__ __launch_bounds__(256) void k_wprep(const float* __restrict__ W0,
                                               const float* __restrict__ W1,
                                               const float* __restrict__ W2,
                                               unsigned long long* W0p,
                                               unsigned long long* W1p,
                                               unsigned long long* W2p,
                                               float* aS0, float* aS1, float* aS2) {
    int t = threadIdx.x, lane = t & 63, w = t >> 6;
    int b = blockIdx.x;
    if (b < 32) {                                  // W0: [256,128]
        int j = b * 4 + w;
        float asum = 0.f;
        unsigned long long words[4];
        #pragma unroll
        for (int q = 0; q < 4; ++q) {
            float v = W0[(size_t)(lane + 64 * q) * HD + j];
            asum += fabsf(v);
            words[q] = __ballot(v < 0.f);
        }
        #pragma unroll
        for (int off = 32; off; off >>= 1) asum += __shfl_xor(asum, off);
        if (lane == 0) {
            aS0[j] = 2.f * asum / 256.f;
            #pragma unroll
            for (int q = 0; q < 4; ++q) W0p[j * 4 + q] = words[q];
        }
    } else if (b < 64) {                           // W1: [128,128]
        int j = (b - 32) * 4 + w;
        int fl = lane & 15, kk = lane >> 4;
        float asum = 0.f;
        unsigned long long words[2];
        #pragma unroll
        for (int q = 0; q < 2; ++q) {
            float v = W1[(size_t)(fl * 8 + 4 * q + kk) * HD + j];
            asum += fabsf(v);
            words[q] = __ballot(v < 0.f);
        }
        #pragma unroll
        for (int off = 32; off; off >>= 1) asum += __shfl_xor(asum, off);
        if (lane == 0) {
            aS1[j] = 2.f * asum / 128.f;
            W1p[j * 2 + 0] = words[0];
            W1p[j * 2 + 1] = words[1];
        }
    } else {                                       // W2: [128,40]
        int j = (b - 64) * 4 + w;
        int fl = lane & 15, kk = lane >> 4;
        if (j < OUT_DIM) {
            float asum = 0.f;
            unsigned long long words[2];
            #pragma unroll
            for (int q = 0; q < 2; ++q) {
                float v = W2[(size_t)(fl * 8 + 4 * q + kk) * OUT_DIM + j];
                asum += fabsf(v);
                words[q] = __ballot(v < 0.f);
            }
            #pragma unroll
            for (int off = 32; off; off >>= 1) asum += __shfl_xor(asum, off);
            if (lane == 0) {
                aS2[j] = 2.f * asum / 128.f;
                W2p[j * 2 + 0] = words[0];
                W2p[j * 2 + 1] = words[1];
            }
        }
    }
}

// ---------------- layer 0: sign(x-mu) + popcount matmul -> S0 (uint8 = S/2+128) ----------------
__global__ __launch_bounds__(256) void k_x_mm0(const float* __restrict__ x,
                                               const float* __restrict__ muacc, float inv_n,
                                               const unsigned long long* __restrict__ W0p,
                                               unsigned char* __restrict__ S0, int N) {
    __shared__ unsigned long long w0s[128 * 4];
    int tid = threadIdx.x;
    w0s[tid] = W0p[tid];
    w0s[tid + 256] = W0p[tid + 256];
    __syncthreads();
    int lane = tid & 63;
    int row = blockIdx.x * 4 + (tid >> 6);
    if (row >= N) return;
    const float* xr = x + (size_t)row * IN_DIM;
    unsigned long long xw[4];
    #pragma unroll
    for (int w = 0; w < 4; ++w) {
        int c = lane + 64 * w;
        float v = xr[c] - muacc[c] * inv_n;
        xw[w] = __ballot(v < 0.f);
    }
    unsigned int pack = 0;
    #pragma unroll
    for (int t2 = 0; t2 < 2; ++t2) {
        int j = 2 * lane + t2;
        const unsigned long long* wc = &w0s[j * 4];
        int dd = __popcll(xw[0] ^ wc[0]) + __popcll(xw[1] ^ wc[1]) +
                 __popcll(xw[2] ^ wc[2]) + __popcll(xw[3] ^ wc[3]);
        int S = IN_DIM - 2 * dd;   // even, [-256,256]
        int s8 = S >> 1;           // [-128,128]
        if (s8 > 127) s8 = 127;    // only |S|=256 clamps (prob ~0)
        pack |= ((unsigned int)(s8 + 128) & 0xffu) << (8 * t2);
    }
    *(unsigned short*)(S0 + (size_t)row * HD + 2 * lane) = (unsigned short)pack;
}

// ---------------- agg + binarize + fused next popcount matmul ----------------
// wave = 1 dst node; 4 sub-groups x 16 lanes; lane handles 8 features (fl*8..fl*8+7)
// uint8 values are un-biased PER ELEMENT ((float)b - 128 is exact) to avoid the
// catastrophic-cancellation noise of the aggregate-unbias variant.
template <int OUTC>
__global__ __launch_bounds__(256) void k_agg_mm(const unsigned char* __restrict__ Sin, // [N][128]
                                                const int* __restrict__ row_ptr,
                                                const long long* __restrict__ cs,
                                                const float* __restrict__ dinv,
                                                const float* __restrict__ alphaS,
                                                const float* __restrict__ bias,
                                                const unsigned long long* __restrict__ Wnp,
                                                unsigned char* __restrict__ Sout, int N) {
    __shared__ unsigned long long wsm[OUTC * 2];
    int tid = threadIdx.x;
    for (int i = tid; i < OUTC * 2; i += 256) wsm[i] = Wnp[i];
    __syncthreads();
    int lane = tid & 63;
    int d = blockIdx.x * 4 + (tid >> 6);
    if (d >= N) return;
    int sub = lane >> 4;       // edge slot 0..3
    int fl  = lane & 15;       // feature group (8 bytes)
    float acc[8];
    #pragma unroll
    for (int k = 0; k < 8; ++k) acc[k] = 0.f;
    if (sub == 0) {            // self loop
        float dv = dinv[d];
        float nrm = dv * dv;
        unsigned long long row = *(const unsigned long long*)(Sin + (size_t)d * HD + fl * 8);
        unsigned int lo = (unsigned int)row, hi = (unsigned int)(row >> 32);
        #pragma unroll
        for (int k = 0; k < 4; ++k) {
            acc[k]     = fmaf(nrm, (float)((lo >> (8 * k)) & 0xffu) - 128.f, acc[k]);
            acc[k + 4] = fmaf(nrm, (float)((hi >> (8 * k)) & 0xffu) - 128.f, acc[k + 4]);
        }
    }
    int e0 = row_ptr[d], e1 = row_ptr[d + 1];
    for (int e = e0 + sub; e < e1; e += 4) {
        long long p = cs[e];
        int s = (int)(unsigned int)p;
        float nrm = __int_as_float((int)(p >> 32));
        unsigned long long row = *(const unsigned long long*)(Sin + (size_t)s * HD + fl * 8);
        unsigned int lo = (unsigned int)row, hi = (unsigned int)(row >> 32);
        #pragma unroll
        for (int k = 0; k < 4; ++k) {
            acc[k]     = fmaf(nrm, (float)((lo >> (8 * k)) & 0xffu) - 128.f, acc[k]);
            acc[k + 4] = fmaf(nrm, (float)((hi >> (8 * k)) & 0xffu) - 128.f, acc[k + 4]);
        }
    }
    // reduce across the 4 sub-groups
    #pragma unroll
    for (int k = 0; k < 8; ++k) {
        acc[k] += __shfl_xor(acc[k], 16);
        acc[k] += __shfl_xor(acc[k], 32);
    }
    // activation sign bits
    unsigned int m8 = 0;
    #pragma unroll
    for (int k = 0; k < 8; ++k) {
        int f = fl * 8 + k;
        float v = alphaS[f] * acc[k] + bias[f];
        if (v < 0.f) m8 |= (1u << k);
    }
    // assemble 128-bit sign vector: word q=k>>2, bit (fl + 16*(k&3))
    unsigned long long x0 = 0, x1 = 0;
    #pragma unroll
    for (int k = 0; k < 4; ++k) {
        unsigned long long bk = __ballot((m8 >> k) & 1u);
        x0 |= (bk & 0xffffULL) << (16 * k);
    }
    #pragma unroll
    for (int k = 4; k < 8; ++k) {
        unsigned long long bk = __ballot((m8 >> k) & 1u);
        x1 |= (bk & 0xffffULL) << (16 * (k - 4));
    }
    if (OUTC == 128) {
        unsigned int pack = 0;
        #pragma unroll
        for (int t2 = 0; t2 < 2; ++t2) {
            int j = 2 * lane + t2;
            int dd = __popcll(x0 ^ wsm[j * 2]) + __popcll(x1 ^ wsm[j * 2 + 1]);
            int S = HD - 2 * dd;  // even, [-128,128]
            pack |= ((unsigned int)((S >> 1) + 128) & 0xffu) << (8 * t2);
        }
        *(unsigned short*)(Sout + (size_t)d * HD + 2 * lane) = (unsigned short)pack;
    } else {
        int p8 = 128;  // biased zero padding
        if (lane < OUTC) {
            int dd = __popcll(x0 ^ wsm[lane * 2]) + __popcll(x1 ^ wsm[lane * 2 + 1]);
            p8 = ((HD - 2 * dd) >> 1) + 128;
        }
        Sout[(size_t)d * S2_STRIDE + lane] = (unsigned char)p8;
    }
}

// ---------------- final agg + log_softmax ----------------
// wave = 1 dst node; 4 sub-groups x 16 lanes; lane handles 4 features (fl*4..fl*4+3)
__global__ __launch_bounds__(256) void k_agg_out(const unsigned char* __restrict__ S2, // [N][64]
                                                 const int* __restrict__ row_ptr,
                                                 const long long* __restrict__ cs,
                                                 const float* __restrict__ dinv,
                                                 const float* __restrict__ alphaS2,
                                                 const float* __restrict__ b2,
                                                 float* __restrict__ out, int N) {
    int tid = threadIdx.x, lane = tid & 63;
    int d = blockIdx.x * 4 + (tid >> 6);
    if (d >= N) return;
    int sub = lane >> 4;
    int fl  = lane & 15;
    float acc[4] = {0.f, 0.f, 0.f, 0.f};
    if (sub == 0) {            // self loop
        float dv = dinv[d];
        float nrm = dv * dv;
        unsigned int r4 = *(const unsigned int*)(S2 + (size_t)d * S2_STRIDE + fl * 4);
        #pragma unroll
        for (int k = 0; k < 4; ++k)
            acc[k] = fmaf(nrm, (float)((r4 >> (8 * k)) & 0xffu) - 128.f, acc[k]);
    }
    int e0 = row_ptr[d], e1 = row_ptr[d + 1];
    for (int e = e0 + sub; e < e1; e += 4) {
        long long p = cs[e];
        int s = (int)(unsigned int)p;
        float nrm = __int_as_float((int)(p >> 32));
        unsigned int r4 = *(const unsigned int*)(S2 + (size_t)s * S2_STRIDE + fl * 4);
        #pragma unroll
        for (int k = 0; k < 4; ++k)
            acc[k] = fmaf(nrm, (float)((r4 >> (8 * k)) & 0xffu) - 128.f, acc[k]);
    }
    #pragma unroll
    for (int k = 0; k < 4; ++k) {
        acc[k] += __shfl_xor(acc[k], 16);
        acc[k] += __shfl_xor(acc[k], 32);
    }
    float h[4];
    float mymax = -INFINITY;
    #pragma unroll
    for (int k = 0; k < 4; ++k) {
        int f = fl * 4 + k;
        h[k] = (f < OUT_DIM) ? (alphaS2[f] * acc[k] + b2[f]) : -INFINITY;
        mymax = fmaxf(mymax, h[k]);
    }
    #pragma unroll
    for (int off = 1; off < 16; off <<= 1) mymax = fmaxf(mymax, __shfl_xor(mymax, off));
    float s4 = 0.f;
    #pragma unroll
    for (int k = 0; k < 4; ++k) {
        if (fl * 4 + k < OUT_DIM) s4 += expf(h[k] - mymax);
    }
    #pragma unroll
    for (int off = 1; off < 16; off <<= 1) s4 += __shfl_xor(s4, off);
    float lse = mymax + logf(s4);
    if (sub == 0 && fl < OUT_DIM / 4) {
        float4 o;
        o.x = h[0] - lse; o.y = h[1] - lse; o.z = h[2] - lse; o.w = h[3] - lse;
        *(float4*)(out + (size_t)d * OUT_DIM + fl * 4) = o;
    }
}

// ---------------- launcher ----------------
extern "C" void kernel_launch(void* const* d_in, const int* in_sizes, int n_in,
                              void* d_out, int out_size, void* d_ws, size_t ws_size,
                              hipStream_t stream) {
    const float* x  = (const float*)d_in[0];
    const int*   ei = (const int*)d_in[1];
    const float* W0 = (const float*)d_in[2];
    const float* b0 = (const float*)d_in[3];
    const float* W1 = (const float*)d_in[4];
    const float* b1 = (const float*)d_in[5];
    const float* W2 = (const float*)d_in[6];
    const float* b2 = (const float*)d_in[7];
    float* out = (float*)d_out;

    int N = in_sizes[0] / IN_DIM;
    int E = in_sizes[1] / 2;

    char* ws = (char*)d_ws;
    size_t off = 0;
    auto alloc = [&](size_t bytes) -> void* {
        off = (off + 255) & ~(size_t)255;
        void* p = (void*)(ws + off);
        off += bytes;
        return p;
    };
    float* muacc  = (float*)alloc(256 * 4);
    int*   deg    = (int*)alloc((size_t)N * 4);
    float* dinv   = (float*)alloc((size_t)N * 4);
    int*   rowp   = (int*)alloc(((size_t)N + 1) * 4);
    int*   cursor = (int*)alloc((size_t)N * 4);
    int*   bp     = (int*)alloc(512 * 4);
    int*   bps    = (int*)alloc(512 * 4);
    long long* cs = (long long*)alloc((size_t)E * 8);
    unsigned char* S0 = (unsigned char*)alloc((size_t)N * HD);
    unsigned char* S1 = (unsigned char*)alloc((size_t)N * HD);
    unsigned char* S2 = (unsigned char*)alloc((size_t)N * S2_STRIDE);
    unsigned long long* W0p = (unsigned long long*)alloc(128 * 4 * 8);
    unsigned long long* W1p = (unsigned long long*)alloc(128 * 2 * 8);
    unsigned long long* W2p = (unsigned long long*)alloc(40 * 2 * 8);
    float* aS0 = (float*)alloc(128 * 4);
    float* aS1 = (float*)alloc(128 * 4);
    float* aS2 = (float*)alloc(40 * 4);

    int nb256 = (N + 255) / 256;
    int ebl = (E + 255) / 256;
    float inv_n = 1.0f / (float)N;

    k_init<<<dim3(nb256), dim3(256), 0, stream>>>(deg, muacc, N);
    k_colsum<<<dim3((N + 127) / 128), dim3(256), 0, stream>>>(x, N, muacc);
    k_deg<<<dim3(ebl), dim3(256), 0, stream>>>(ei, E, deg);
    k_bp<<<dim3(nb256), dim3(256), 0, stream>>>(deg, N, bp);
    k_scanbp<<<dim3(1), dim3(512), 0, stream>>>(bp, nb256, bps);
    k_rowptr<<<dim3(nb256), dim3(256), 0, stream>>>(deg, bps, N, E, rowp, cursor, dinv);
    k_scatter<<<dim3(ebl), dim3(256), 0, stream>>>(ei, E, dinv, cursor, cs);
    k_wprep<<<dim3(74), dim3(256), 0, stream>>>(W0, W1, W2, W0p, W1p, W2p, aS0, aS1, aS2);

    int nb4 = (N + 3) / 4;
    k_x_mm0<<<dim3(nb4), dim3(256), 0, stream>>>(x, muacc, inv_n, W0p, S0, N);
    k_agg_mm<128><<<dim3(nb4), dim3(256), 0, stream>>>(S0, rowp, cs, dinv, aS0, b0, W1p, S1, N);
    k_agg_mm<40><<<dim3(nb4), dim3(256), 0, stream>>>(S1, rowp, cs, dinv, aS1, b1, W2p, S2, N);
    k_agg_out<<<dim3(nb4), dim3(256), 0, stream>>>(S2, rowp, cs, dinv, aS2, b2, out, N);
    (void)out_size; (void)ws_size; (void)n_in;
}

// Round 4
// 605.254 us; speedup vs baseline: 1.4418x; 1.0292x over previous
//
#include <hip/hip_runtime.h>
#include <math.h>

#define IN_DIM 256
#define HD 128
#define OUT_DIM 40
#define S2_STRIDE 64
#define NB_CS 512   // colsum blocks in fuse1

// ---------------- init ----------------
__global__ __launch_bounds__(256) void k_init(int* deg, float* muacc, int N) {
    int i = blockIdx.x * 256 + threadIdx.x;
    if (i < N) deg[i] = 1;                 // self-loop
    if (blockIdx.x == 0 && threadIdx.x < 256) muacc[threadIdx.x] = 0.f;
}

// ---------------- fuse1: colsum (float4) + deg + wprep ----------------
// W0p: word q (q=0..3) bit l <-> row 4l+q           [x_mm0 float4 convention]
// W1p/W2p: word q (q=0,1) bit b <-> row (b&7)*16 + (b>>3) + 8q  [agg 8-slot convention]
__global__ __launch_bounds__(256) void k_fuse1(const float* __restrict__ x, int N,
                                               float* __restrict__ muacc,
                                               const int* __restrict__ ei, int E, int* deg,
                                               int ebl,
                                               const float* __restrict__ W0,
                                               const float* __restrict__ W1,
                                               const float* __restrict__ W2,
                                               unsigned long long* W0p,
                                               unsigned long long* W1p,
                                               unsigned long long* W2p,
                                               float* aS0, float* aS1, float* aS2) {
    __shared__ float lds[256];
    int b = blockIdx.x, tid = threadIdx.x;
    if (b < NB_CS) {                       // ---- colsum ----
        size_t F4 = (size_t)N * (IN_DIM / 4);
        size_t stride = (size_t)NB_CS * 256;
        float a0 = 0.f, a1 = 0.f, a2 = 0.f, a3 = 0.f;
        const float4* x4 = (const float4*)x;
        for (size_t i = (size_t)b * 256 + tid; i < F4; i += stride) {
            float4 v = x4[i];
            a0 += v.x; a1 += v.y; a2 += v.z; a3 += v.w;
        }
        lds[tid] = 0.f;
        __syncthreads();
        int c0 = (tid * 4) & 255;
        atomicAdd(&lds[c0], a0);
        atomicAdd(&lds[c0 + 1], a1);
        atomicAdd(&lds[c0 + 2], a2);
        atomicAdd(&lds[c0 + 3], a3);
        __syncthreads();
        atomicAdd(&muacc[tid], lds[tid]);
    } else if (b < NB_CS + ebl) {          // ---- deg ----
        int e = (b - NB_CS) * 256 + tid;
        if (e < E) atomicAdd(&deg[ei[E + e]], 1);
    } else {                               // ---- wprep ----
        int b2 = b - NB_CS - ebl;
        int lane = tid & 63, w = tid >> 6;
        if (b2 < 32) {                     // W0: [256,128]
            int j = b2 * 4 + w;
            float asum = 0.f;
            unsigned long long words[4];
            #pragma unroll
            for (int q = 0; q < 4; ++q) {
                float v = W0[(size_t)(4 * lane + q) * HD + j];
                asum += fabsf(v);
                words[q] = __ballot(v < 0.f);
            }
            #pragma unroll
            for (int off = 32; off; off >>= 1) asum += __shfl_xor(asum, off);
            if (lane == 0) {
                aS0[j] = 2.f * asum / 256.f;
                #pragma unroll
                for (int q = 0; q < 4; ++q) W0p[j * 4 + q] = words[q];
            }
        } else if (b2 < 64) {              // W1: [128,128]
            int j = (b2 - 32) * 4 + w;
            int fl = lane & 7, idx = lane >> 3;
            float asum = 0.f;
            unsigned long long words[2];
            #pragma unroll
            for (int q = 0; q < 2; ++q) {
                float v = W1[(size_t)(fl * 16 + idx + 8 * q) * HD + j];
                asum += fabsf(v);
                words[q] = __ballot(v < 0.f);
            }
            #pragma unroll
            for (int off = 32; off; off >>= 1) asum += __shfl_xor(asum, off);
            if (lane == 0) {
                aS1[j] = 2.f * asum / 128.f;
                W1p[j * 2 + 0] = words[0];
                W1p[j * 2 + 1] = words[1];
            }
        } else {                           // W2: [128,40]
            int j = (b2 - 64) * 4 + w;
            int fl = lane & 7, idx = lane >> 3;
            if (j < OUT_DIM) {
                float asum = 0.f;
                unsigned long long words[2];
                #pragma unroll
                for (int q = 0; q < 2; ++q) {
                    float v = W2[(size_t)(fl * 16 + idx + 8 * q) * OUT_DIM + j];
                    asum += fabsf(v);
                    words[q] = __ballot(v < 0.f);
                }
                #pragma unroll
                for (int off = 32; off; off >>= 1) asum += __shfl_xor(asum, off);
                if (lane == 0) {
                    aS2[j] = 2.f * asum / 128.f;
                    W2p[j * 2 + 0] = words[0];
                    W2p[j * 2 + 1] = words[1];
                }
            }
        }
    }
}

// ---------------- CSR build (small kernels) ----------------
__global__ __launch_bounds__(256) void k_bp(const int* __restrict__ deg, int N, int* bp) {
    __shared__ int sm[256];
    int i = blockIdx.x * 256 + threadIdx.x;
    sm[threadIdx.x] = (i < N) ? (deg[i] - 1) : 0;
    __syncthreads();
    for (int off = 128; off; off >>= 1) {
        if (threadIdx.x < off) sm[threadIdx.x] += sm[threadIdx.x + off];
        __syncthreads();
    }
    if (threadIdx.x == 0) bp[blockIdx.x] = sm[0];
}

__global__ __launch_bounds__(512) void k_scanbp(const int* __restrict__ bp, int NB, int* bps) {
    __shared__ int sm[512];
    int t = threadIdx.x;
    int v = (t < NB) ? bp[t] : 0;
    sm[t] = v;
    __syncthreads();
    for (int off = 1; off < 512; off <<= 1) {
        int add = (t >= off) ? sm[t - off] : 0;
        __syncthreads();
        sm[t] += add;
        __syncthreads();
    }
    if (t < NB) bps[t] = sm[t] - v;        // exclusive
}

__global__ __launch_bounds__(256) void k_rowptr(const int* __restrict__ deg,
                                                const int* __restrict__ bps, int N, int E,
                                                int* row_ptr, int* cursor, float* dinv) {
    __shared__ int wsum[4];
    int t = threadIdx.x, lane = t & 63, w = t >> 6;
    int i = blockIdx.x * 256 + t;
    int c = (i < N) ? (deg[i] - 1) : 0;
    int v = c;
    #pragma unroll
    for (int off = 1; off < 64; off <<= 1) {
        int n = __shfl_up(v, off);
        if (lane >= off) v += n;
    }
    if (lane == 63) wsum[w] = v;
    __syncthreads();
    int wo = 0;
    for (int k = 0; k < w; ++k) wo += wsum[k];
    int excl = bps[blockIdx.x] + wo + v - c;
    if (i < N) {
        row_ptr[i] = excl;
        cursor[i] = excl;
        dinv[i] = (float)(1.0 / sqrt((double)deg[i]));
    }
    if (blockIdx.x == 0 && t == 0) row_ptr[N] = E;
}

// ---------------- fuse2: edge scatter + layer-0 binarize/popcount matmul ----------------
__global__ __launch_bounds__(256) void k_fuse2(const int* __restrict__ ei, int E,
                                               const float* __restrict__ dinv, int* cursor,
                                               long long* __restrict__ cs, int nbScat,
                                               const float* __restrict__ x,
                                               const float* __restrict__ muacc, float inv_n,
                                               const unsigned long long* __restrict__ W0p,
                                               unsigned char* __restrict__ S0, int N) {
    __shared__ unsigned long long w0s[128 * 4];
    int b = blockIdx.x, tid = threadIdx.x;
    if (b < nbScat) {                      // ---- scatter ----
        int e = b * 256 + tid;
        if (e >= E) return;
        int s = ei[e];
        int d = ei[E + e];
        int pos = atomicAdd(&cursor[d], 1);
        float nrm = dinv[s] * dinv[d];
        long long v = (long long)(unsigned int)s |
                      ((long long)(unsigned int)__float_as_int(nrm) << 32);
        __builtin_nontemporal_store(v, &cs[pos]);
    } else {                               // ---- x_mm0 ----
        w0s[tid] = W0p[tid];
        w0s[tid + 256] = W0p[tid + 256];
        __syncthreads();
        int lane = tid & 63;
        int row = (b - nbScat) * 4 + (tid >> 6);
        if (row >= N) return;
        float4 xv = ((const float4*)(x + (size_t)row * IN_DIM))[lane];
        float4 ms = ((const float4*)muacc)[lane];
        unsigned long long xw[4];
        xw[0] = __ballot(xv.x < ms.x * inv_n);
        xw[1] = __ballot(xv.y < ms.y * inv_n);
        xw[2] = __ballot(xv.z < ms.z * inv_n);
        xw[3] = __ballot(xv.w < ms.w * inv_n);
        unsigned int pack = 0;
        #pragma unroll
        for (int t2 = 0; t2 < 2; ++t2) {
            int j = 2 * lane + t2;
            const unsigned long long* wc = &w0s[j * 4];
            int dd = __popcll(xw[0] ^ wc[0]) + __popcll(xw[1] ^ wc[1]) +
                     __popcll(xw[2] ^ wc[2]) + __popcll(xw[3] ^ wc[3]);
            int S = IN_DIM - 2 * dd;   // even, [-256,256]
            int s8 = S >> 1;
            if (s8 > 127) s8 = 127;
            pack |= ((unsigned int)(s8 + 128) & 0xffu) << (8 * t2);
        }
        *(unsigned short*)(S0 + (size_t)row * HD + 2 * lane) = (unsigned short)pack;
    }
}

// ---------------- agg + binarize + fused next popcount matmul (8-slot ILP) ----------------
// wave = 1 dst; 8 sub-groups x 8 lanes; lane loads 16B (16 features fl*16..fl*16+15)
template <int OUTC>
__global__ __launch_bounds__(256) void k_agg_mm(const unsigned char* __restrict__ Sin, // [N][128]
                                                const int* __restrict__ row_ptr,
                                                const long long* __restrict__ cs,
                                                const float* __restrict__ dinv,
                                                const float* __restrict__ alphaS,
                                                const float* __restrict__ bias,
                                                const unsigned long long* __restrict__ Wnp,
                                                unsigned char* __restrict__ Sout, int N) {
    __shared__ unsigned long long wsm[OUTC * 2];
    int tid = threadIdx.x;
    for (int i = tid; i < OUTC * 2; i += 256) wsm[i] = Wnp[i];
    __syncthreads();
    int lane = tid & 63;
    int d = blockIdx.x * 4 + (tid >> 6);
    if (d >= N) return;
    int sub = lane >> 3;       // edge slot 0..7
    int fl  = lane & 7;        // 16-byte feature group
    float acc[16];
    #pragma unroll
    for (int k = 0; k < 16; ++k) acc[k] = 0.f;
    if (sub == 0) {            // self loop
        float dv = dinv[d];
        float nrm = dv * dv;
        uint4 r = *(const uint4*)(Sin + (size_t)d * HD + fl * 16);
        unsigned int ws_[4] = {r.x, r.y, r.z, r.w};
        #pragma unroll
        for (int w = 0; w < 4; ++w)
            #pragma unroll
            for (int k = 0; k < 4; ++k)
                acc[w * 4 + k] = fmaf(nrm, (float)((ws_[w] >> (8 * k)) & 0xffu) - 128.f,
                                      acc[w * 4 + k]);
    }
    int e0 = row_ptr[d], e1 = row_ptr[d + 1];
    for (int e = e0 + sub; e < e1; e += 8) {
        long long p = cs[e];
        int s = (int)(unsigned int)p;
        float nrm = __int_as_float((int)(p >> 32));
        uint4 r = *(const uint4*)(Sin + (size_t)s * HD + fl * 16);
        unsigned int ws_[4] = {r.x, r.y, r.z, r.w};
        #pragma unroll
        for (int w = 0; w < 4; ++w)
            #pragma unroll
            for (int k = 0; k < 4; ++k)
                acc[w * 4 + k] = fmaf(nrm, (float)((ws_[w] >> (8 * k)) & 0xffu) - 128.f,
                                      acc[w * 4 + k]);
    }
    // reduce across the 8 sub-groups
    #pragma unroll
    for (int k = 0; k < 16; ++k) {
        acc[k] += __shfl_xor(acc[k], 8);
        acc[k] += __shfl_xor(acc[k], 16);
        acc[k] += __shfl_xor(acc[k], 32);
    }
    // activation sign bits: feature f = fl*16 + k
    unsigned int m16 = 0;
    #pragma unroll
    for (int k = 0; k < 16; ++k) {
        int f = fl * 16 + k;
        float v = alphaS[f] * acc[k] + bias[f];
        if (v < 0.f) m16 |= (1u << k);
    }
    // assemble 128-bit sign vector: word q=k>>3, bit 8*(k&7)+fl
    unsigned long long x0 = 0, x1 = 0;
    #pragma unroll
    for (int k = 0; k < 8; ++k) {
        unsigned long long bk = __ballot((m16 >> k) & 1u);
        x0 |= (bk & 0xffULL) << (8 * k);
    }
    #pragma unroll
    for (int k = 8; k < 16; ++k) {
        unsigned long long bk = __ballot((m16 >> k) & 1u);
        x1 |= (bk & 0xffULL) << (8 * (k - 8));
    }
    if (OUTC == 128) {
        unsigned int pack = 0;
        #pragma unroll
        for (int t2 = 0; t2 < 2; ++t2) {
            int j = 2 * lane + t2;
            int dd = __popcll(x0 ^ wsm[j * 2]) + __popcll(x1 ^ wsm[j * 2 + 1]);
            int S = HD - 2 * dd;  // even, [-128,128]
            pack |= ((unsigned int)((S >> 1) + 128) & 0xffu) << (8 * t2);
        }
        *(unsigned short*)(Sout + (size_t)d * HD + 2 * lane) = (unsigned short)pack;
    } else {
        int p8 = 128;  // biased zero padding
        if (lane < OUTC) {
            int dd = __popcll(x0 ^ wsm[lane * 2]) + __popcll(x1 ^ wsm[lane * 2 + 1]);
            p8 = ((HD - 2 * dd) >> 1) + 128;
        }
        Sout[(size_t)d * S2_STRIDE + lane] = (unsigned char)p8;
    }
}

// ---------------- final agg + log_softmax (8-slot ILP) ----------------
// wave = 1 dst; 8 sub x 8 lanes; lane loads 8B (features fl*8..fl*8+7); row stride 64
__global__ __launch_bounds__(256) void k_agg_out(const unsigned char* __restrict__ S2, // [N][64]
                                                 const int* __restrict__ row_ptr,
                                                 const long long* __restrict__ cs,
                                                 const float* __restrict__ dinv,
                                                 const float* __restrict__ alphaS2,
                                                 const float* __restrict__ b2,
                                                 float* __restrict__ out, int N) {
    int tid = threadIdx.x, lane = tid & 63;
    int d = blockIdx.x * 4 + (tid >> 6);
    if (d >= N) return;
    int sub = lane >> 3;
    int fl  = lane & 7;
    float acc[8];
    #pragma unroll
    for (int k = 0; k < 8; ++k) acc[k] = 0.f;
    if (sub == 0) {            // self loop
        float dv = dinv[d];
        float nrm = dv * dv;
        unsigned long long r = *(const unsigned long long*)(S2 + (size_t)d * S2_STRIDE + fl * 8);
        unsigned int lo = (unsigned int)r, hi = (unsigned int)(r >> 32);
        #pragma unroll
        for (int k = 0; k < 4; ++k) {
            acc[k]     = fmaf(nrm, (float)((lo >> (8 * k)) & 0xffu) - 128.f, acc[k]);
            acc[k + 4] = fmaf(nrm, (float)((hi >> (8 * k)) & 0xffu) - 128.f, acc[k + 4]);
        }
    }
    int e0 = row_ptr[d], e1 = row_ptr[d + 1];
    for (int e = e0 + sub; e < e1; e += 8) {
        long long p = cs[e];
        int s = (int)(unsigned int)p;
        float nrm = __int_as_float((int)(p >> 32));
        unsigned long long r = *(const unsigned long long*)(S2 + (size_t)s * S2_STRIDE + fl * 8);
        unsigned int lo = (unsigned int)r, hi = (unsigned int)(r >> 32);
        #pragma unroll
        for (int k = 0; k < 4; ++k) {
            acc[k]     = fmaf(nrm, (float)((lo >> (8 * k)) & 0xffu) - 128.f, acc[k]);
            acc[k + 4] = fmaf(nrm, (float)((hi >> (8 * k)) & 0xffu) - 128.f, acc[k + 4]);
        }
    }
    #pragma unroll
    for (int k = 0; k < 8; ++k) {
        acc[k] += __shfl_xor(acc[k], 8);
        acc[k] += __shfl_xor(acc[k], 16);
        acc[k] += __shfl_xor(acc[k], 32);
    }
    // features f = fl*8+k: valid exactly when fl < 5
    float h[8];
    float mymax = -INFINITY;
    bool valid = (fl < OUT_DIM / 8);
    #pragma unroll
    for (int k = 0; k < 8; ++k) {
        int f = fl * 8 + k;
        h[k] = valid ? (alphaS2[f] * acc[k] + b2[f]) : -INFINITY;
        mymax = fmaxf(mymax, h[k]);
    }
    #pragma unroll
    for (int off = 1; off < 8; off <<= 1) mymax = fmaxf(mymax, __shfl_xor(mymax, off));
    float s8 = 0.f;
    if (valid) {
        #pragma unroll
        for (int k = 0; k < 8; ++k) s8 += expf(h[k] - mymax);
    }
    #pragma unroll
    for (int off = 1; off < 8; off <<= 1) s8 += __shfl_xor(s8, off);
    float lse = mymax + logf(s8);
    if (lane < OUT_DIM / 8) {   // sub==0 && fl<5
        float4 o0, o1;
        o0.x = h[0] - lse; o0.y = h[1] - lse; o0.z = h[2] - lse; o0.w = h[3] - lse;
        o1.x = h[4] - lse; o1.y = h[5] - lse; o1.z = h[6] - lse; o1.w = h[7] - lse;
        float* op = out + (size_t)d * OUT_DIM + fl * 8;
        *(float4*)op = o0;
        *(float4*)(op + 4) = o1;
    }
}

// ---------------- launcher ----------------
extern "C" void kernel_launch(void* const* d_in, const int* in_sizes, int n_in,
                              void* d_out, int out_size, void* d_ws, size_t ws_size,
                              hipStream_t stream) {
    const float* x  = (const float*)d_in[0];
    const int*   ei = (const int*)d_in[1];
    const float* W0 = (const float*)d_in[2];
    const float* b0 = (const float*)d_in[3];
    const float* W1 = (const float*)d_in[4];
    const float* b1 = (const float*)d_in[5];
    const float* W2 = (const float*)d_in[6];
    const float* b2 = (const float*)d_in[7];
    float* out = (float*)d_out;

    int N = in_sizes[0] / IN_DIM;
    int E = in_sizes[1] / 2;

    char* ws = (char*)d_ws;
    size_t off = 0;
    auto alloc = [&](size_t bytes) -> void* {
        off = (off + 255) & ~(size_t)255;
        void* p = (void*)(ws + off);
        off += bytes;
        return p;
    };
    float* muacc  = (float*)alloc(256 * 4);
    int*   deg    = (int*)alloc((size_t)N * 4);
    float* dinv   = (float*)alloc((size_t)N * 4);
    int*   rowp   = (int*)alloc(((size_t)N + 1) * 4);
    int*   cursor = (int*)alloc((size_t)N * 4);
    int*   bp     = (int*)alloc(512 * 4);
    int*   bps    = (int*)alloc(512 * 4);
    long long* cs = (long long*)alloc((size_t)E * 8);
    unsigned char* S0 = (unsigned char*)alloc((size_t)N * HD);
    unsigned char* S1 = (unsigned char*)alloc((size_t)N * HD);
    unsigned char* S2 = (unsigned char*)alloc((size_t)N * S2_STRIDE);
    unsigned long long* W0p = (unsigned long long*)alloc(128 * 4 * 8);
    unsigned long long* W1p = (unsigned long long*)alloc(128 * 2 * 8);
    unsigned long long* W2p = (unsigned long long*)alloc(40 * 2 * 8);
    float* aS0 = (float*)alloc(128 * 4);
    float* aS1 = (float*)alloc(128 * 4);
    float* aS2 = (float*)alloc(40 * 4);

    int nb256 = (N + 255) / 256;
    int ebl = (E + 255) / 256;
    float inv_n = 1.0f / (float)N;

    k_init<<<dim3(nb256), dim3(256), 0, stream>>>(deg, muacc, N);
    k_fuse1<<<dim3(NB_CS + ebl + 74), dim3(256), 0, stream>>>(
        x, N, muacc, ei, E, deg, ebl, W0, W1, W2, W0p, W1p, W2p, aS0, aS1, aS2);
    k_bp<<<dim3(nb256), dim3(256), 0, stream>>>(deg, N, bp);
    k_scanbp<<<dim3(1), dim3(512), 0, stream>>>(bp, nb256, bps);
    k_rowptr<<<dim3(nb256), dim3(256), 0, stream>>>(deg, bps, N, E, rowp, cursor, dinv);

    int nb4 = (N + 3) / 4;
    k_fuse2<<<dim3(ebl + nb4), dim3(256), 0, stream>>>(
        ei, E, dinv, cursor, cs, ebl, x, muacc, inv_n, W0p, S0, N);
    k_agg_mm<128><<<dim3(nb4), dim3(256), 0, stream>>>(S0, rowp, cs, dinv, aS0, b0, W1p, S1, N);
    k_agg_mm<40><<<dim3(nb4), dim3(256), 0, stream>>>(S1, rowp, cs, dinv, aS1, b1, W2p, S2, N);
    k_agg_out<<<dim3(nb4), dim3(256), 0, stream>>>(S2, rowp, cs, dinv, aS2, b2, out, N);
    (void)out_size; (void)ws_size; (void)n_in;
}

// Round 5
// 512.551 us; speedup vs baseline: 1.7026x; 1.1809x over previous
//
#include <hip/hip_runtime.h>
#include <math.h>

#define IN_DIM 256
#define HD 128
#define OUT_DIM 40
#define S2_STRIDE 64
#define NB_CS 512   // colsum blocks in fuse1

// ---------------- init ----------------
__global__ __launch_bounds__(256) void k_init(int* deg, float* muacc, int N) {
    int i = blockIdx.x * 256 + threadIdx.x;
    if (i < N) deg[i] = 1;                 // self-loop
    if (blockIdx.x == 0 && threadIdx.x < 256) muacc[threadIdx.x] = 0.f;
}

// ---------------- fuse1: colsum (float4) + deg/rank + wprep ----------------
// W0p: word q (q=0..3) bit l <-> row 4l+q                 [x_mm0 float4 convention]
// W1p/W2p: word q (q=0,1) bit (fl+16*kk) <-> row fl*8+4q+kk  [agg 4-slot convention]
__global__ __launch_bounds__(256) void k_fuse1(const float* __restrict__ x, int N,
                                               float* __restrict__ muacc,
                                               const int* __restrict__ ei, int E, int* deg,
                                               int* __restrict__ rank, int ebl,
                                               const float* __restrict__ W0,
                                               const float* __restrict__ W1,
                                               const float* __restrict__ W2,
                                               unsigned long long* W0p,
                                               unsigned long long* W1p,
                                               unsigned long long* W2p,
                                               float* aS0, float* aS1, float* aS2) {
    __shared__ float lds[256];
    int b = blockIdx.x, tid = threadIdx.x;
    if (b < NB_CS) {                       // ---- colsum ----
        size_t F4 = (size_t)N * (IN_DIM / 4);
        size_t stride = (size_t)NB_CS * 256;
        float a0 = 0.f, a1 = 0.f, a2 = 0.f, a3 = 0.f;
        const float4* x4 = (const float4*)x;
        for (size_t i = (size_t)b * 256 + tid; i < F4; i += stride) {
            float4 v = x4[i];
            a0 += v.x; a1 += v.y; a2 += v.z; a3 += v.w;
        }
        lds[tid] = 0.f;
        __syncthreads();
        int c0 = (tid * 4) & 255;
        atomicAdd(&lds[c0], a0);
        atomicAdd(&lds[c0 + 1], a1);
        atomicAdd(&lds[c0 + 2], a2);
        atomicAdd(&lds[c0 + 3], a3);
        __syncthreads();
        atomicAdd(&muacc[tid], lds[tid]);
    } else if (b < NB_CS + ebl) {          // ---- deg + per-edge rank ----
        int e = (b - NB_CS) * 256 + tid;
        if (e < E) {
            int old = atomicAdd(&deg[ei[E + e]], 1);   // starts at 1 (self-loop)
            rank[e] = old - 1;                         // rank among real edges of dst
        }
    } else {                               // ---- wprep ----
        int b2 = b - NB_CS - ebl;
        int lane = tid & 63, w = tid >> 6;
        if (b2 < 32) {                     // W0: [256,128]
            int j = b2 * 4 + w;
            float asum = 0.f;
            unsigned long long words[4];
            #pragma unroll
            for (int q = 0; q < 4; ++q) {
                float v = W0[(size_t)(4 * lane + q) * HD + j];
                asum += fabsf(v);
                words[q] = __ballot(v < 0.f);
            }
            #pragma unroll
            for (int off = 32; off; off >>= 1) asum += __shfl_xor(asum, off);
            if (lane == 0) {
                aS0[j] = 2.f * asum / 256.f;
                #pragma unroll
                for (int q = 0; q < 4; ++q) W0p[j * 4 + q] = words[q];
            }
        } else if (b2 < 64) {              // W1: [128,128]
            int j = (b2 - 32) * 4 + w;
            int fl = lane & 15, kk = lane >> 4;
            float asum = 0.f;
            unsigned long long words[2];
            #pragma unroll
            for (int q = 0; q < 2; ++q) {
                float v = W1[(size_t)(fl * 8 + 4 * q + kk) * HD + j];
                asum += fabsf(v);
                words[q] = __ballot(v < 0.f);
            }
            #pragma unroll
            for (int off = 32; off; off >>= 1) asum += __shfl_xor(asum, off);
            if (lane == 0) {
                aS1[j] = 2.f * asum / 128.f;
                W1p[j * 2 + 0] = words[0];
                W1p[j * 2 + 1] = words[1];
            }
        } else {                           // W2: [128,40]
            int j = (b2 - 64) * 4 + w;
            int fl = lane & 15, kk = lane >> 4;
            if (j < OUT_DIM) {
                float asum = 0.f;
                unsigned long long words[2];
                #pragma unroll
                for (int q = 0; q < 2; ++q) {
                    float v = W2[(size_t)(fl * 8 + 4 * q + kk) * OUT_DIM + j];
                    asum += fabsf(v);
                    words[q] = __ballot(v < 0.f);
                }
                #pragma unroll
                for (int off = 32; off; off >>= 1) asum += __shfl_xor(asum, off);
                if (lane == 0) {
                    aS2[j] = 2.f * asum / 128.f;
                    W2p[j * 2 + 0] = words[0];
                    W2p[j * 2 + 1] = words[1];
                }
            }
        }
    }
}

// ---------------- CSR build (small kernels) ----------------
__global__ __launch_bounds__(256) void k_bp(const int* __restrict__ deg, int N, int* bp) {
    __shared__ int sm[256];
    int i = blockIdx.x * 256 + threadIdx.x;
    sm[threadIdx.x] = (i < N) ? (deg[i] - 1) : 0;
    __syncthreads();
    for (int off = 128; off; off >>= 1) {
        if (threadIdx.x < off) sm[threadIdx.x] += sm[threadIdx.x + off];
        __syncthreads();
    }
    if (threadIdx.x == 0) bp[blockIdx.x] = sm[0];
}

__global__ __launch_bounds__(512) void k_scanbp(const int* __restrict__ bp, int NB, int* bps) {
    __shared__ int sm[512];
    int t = threadIdx.x;
    int v = (t < NB) ? bp[t] : 0;
    sm[t] = v;
    __syncthreads();
    for (int off = 1; off < 512; off <<= 1) {
        int add = (t >= off) ? sm[t - off] : 0;
        __syncthreads();
        sm[t] += add;
        __syncthreads();
    }
    if (t < NB) bps[t] = sm[t] - v;        // exclusive
}

__global__ __launch_bounds__(256) void k_rowptr(const int* __restrict__ deg,
                                                const int* __restrict__ bps, int N, int E,
                                                int* row_ptr, float* dinv) {
    __shared__ int wsum[4];
    int t = threadIdx.x, lane = t & 63, w = t >> 6;
    int i = blockIdx.x * 256 + t;
    int c = (i < N) ? (deg[i] - 1) : 0;
    int v = c;
    #pragma unroll
    for (int off = 1; off < 64; off <<= 1) {
        int n = __shfl_up(v, off);
        if (lane >= off) v += n;
    }
    if (lane == 63) wsum[w] = v;
    __syncthreads();
    int wo = 0;
    for (int k = 0; k < w; ++k) wo += wsum[k];
    int excl = bps[blockIdx.x] + wo + v - c;
    if (i < N) {
        row_ptr[i] = excl;
        dinv[i] = (float)(1.0 / sqrt((double)deg[i]));
    }
    if (blockIdx.x == 0 && t == 0) row_ptr[N] = E;
}

// ---------------- fuse2: atomic-free edge scatter + layer-0 matmul ----------------
__global__ __launch_bounds__(256) void k_fuse2(const int* __restrict__ ei, int E,
                                               const float* __restrict__ dinv,
                                               const int* __restrict__ rowp,
                                               const int* __restrict__ rank,
                                               long long* __restrict__ cs, int nbScat,
                                               const float* __restrict__ x,
                                               const float* __restrict__ muacc, float inv_n,
                                               const unsigned long long* __restrict__ W0p,
                                               unsigned char* __restrict__ S0, int N) {
    __shared__ unsigned long long w0s[128 * 4];
    int b = blockIdx.x, tid = threadIdx.x;
    if (b < nbScat) {                      // ---- scatter (no atomics) ----
        int e = b * 256 + tid;
        if (e >= E) return;
        int s = ei[e];
        int d = ei[E + e];
        int pos = rowp[d] + rank[e];
        float nrm = dinv[s] * dinv[d];
        long long v = (long long)(unsigned int)s |
                      ((long long)(unsigned int)__float_as_int(nrm) << 32);
        __builtin_nontemporal_store(v, &cs[pos]);
    } else {                               // ---- x_mm0 ----
        w0s[tid] = W0p[tid];
        w0s[tid + 256] = W0p[tid + 256];
        __syncthreads();
        int lane = tid & 63;
        int row = (b - nbScat) * 4 + (tid >> 6);
        if (row >= N) return;
        float4 xv = ((const float4*)(x + (size_t)row * IN_DIM))[lane];
        float4 ms = ((const float4*)muacc)[lane];
        unsigned long long xw[4];
        xw[0] = __ballot(xv.x < ms.x * inv_n);
        xw[1] = __ballot(xv.y < ms.y * inv_n);
        xw[2] = __ballot(xv.z < ms.z * inv_n);
        xw[3] = __ballot(xv.w < ms.w * inv_n);
        unsigned int pack = 0;
        #pragma unroll
        for (int t2 = 0; t2 < 2; ++t2) {
            int j = 2 * lane + t2;
            const unsigned long long* wc = &w0s[j * 4];
            int dd = __popcll(xw[0] ^ wc[0]) + __popcll(xw[1] ^ wc[1]) +
                     __popcll(xw[2] ^ wc[2]) + __popcll(xw[3] ^ wc[3]);
            int S = IN_DIM - 2 * dd;   // even, [-256,256]
            int s8 = S >> 1;
            if (s8 > 127) s8 = 127;
            pack |= ((unsigned int)(s8 + 128) & 0xffu) << (8 * t2);
        }
        *(unsigned short*)(S0 + (size_t)row * HD + 2 * lane) = (unsigned short)pack;
    }
}

// ---------------- agg + binarize + fused next popcount matmul ----------------
// wave = 1 dst; 4 slots x 16 lanes; lane loads 8B (features fl*8..fl*8+7);
// edge loop batched 2 at a time (2 gathers in flight per slot).
template <int OUTC>
__global__ __launch_bounds__(256) void k_agg_mm(const unsigned char* __restrict__ Sin, // [N][128]
                                                const int* __restrict__ row_ptr,
                                                const long long* __restrict__ cs,
                                                const float* __restrict__ dinv,
                                                const float* __restrict__ alphaS,
                                                const float* __restrict__ bias,
                                                const unsigned long long* __restrict__ Wnp,
                                                unsigned char* __restrict__ Sout, int N) {
    __shared__ unsigned long long wsm[OUTC * 2];
    int tid = threadIdx.x;
    for (int i = tid; i < OUTC * 2; i += 256) wsm[i] = Wnp[i];
    __syncthreads();
    int lane = tid & 63;
    int d = blockIdx.x * 4 + (tid >> 6);
    if (d >= N) return;
    int sub = lane >> 4;       // edge slot 0..3
    int fl  = lane & 15;       // 8-byte feature group
    float acc[8];
    #pragma unroll
    for (int k = 0; k < 8; ++k) acc[k] = 0.f;
    if (sub == 0) {            // self loop
        float dv = dinv[d];
        float nrm = dv * dv;
        unsigned long long r = *(const unsigned long long*)(Sin + (size_t)d * HD + fl * 8);
        unsigned int lo = (unsigned int)r, hi = (unsigned int)(r >> 32);
        #pragma unroll
        for (int k = 0; k < 4; ++k) {
            acc[k]     = fmaf(nrm, (float)((lo >> (8 * k)) & 0xffu) - 128.f, acc[k]);
            acc[k + 4] = fmaf(nrm, (float)((hi >> (8 * k)) & 0xffu) - 128.f, acc[k + 4]);
        }
    }
    int e0 = row_ptr[d], e1 = row_ptr[d + 1];
    int e = e0 + sub;
    for (; e + 4 < e1; e += 8) {           // 2 edges per iteration
        long long pa = cs[e];
        long long pb = cs[e + 4];
        int sa = (int)(unsigned int)pa;
        int sb = (int)(unsigned int)pb;
        unsigned long long ra = *(const unsigned long long*)(Sin + (size_t)sa * HD + fl * 8);
        unsigned long long rb = *(const unsigned long long*)(Sin + (size_t)sb * HD + fl * 8);
        float na = __int_as_float((int)(pa >> 32));
        float nb = __int_as_float((int)(pb >> 32));
        unsigned int la = (unsigned int)ra, ha = (unsigned int)(ra >> 32);
        unsigned int lb = (unsigned int)rb, hb = (unsigned int)(rb >> 32);
        #pragma unroll
        for (int k = 0; k < 4; ++k) {
            acc[k]     = fmaf(na, (float)((la >> (8 * k)) & 0xffu) - 128.f, acc[k]);
            acc[k + 4] = fmaf(na, (float)((ha >> (8 * k)) & 0xffu) - 128.f, acc[k + 4]);
            acc[k]     = fmaf(nb, (float)((lb >> (8 * k)) & 0xffu) - 128.f, acc[k]);
            acc[k + 4] = fmaf(nb, (float)((hb >> (8 * k)) & 0xffu) - 128.f, acc[k + 4]);
        }
    }
    if (e < e1) {                          // tail
        long long p = cs[e];
        int s = (int)(unsigned int)p;
        float nrm = __int_as_float((int)(p >> 32));
        unsigned long long r = *(const unsigned long long*)(Sin + (size_t)s * HD + fl * 8);
        unsigned int lo = (unsigned int)r, hi = (unsigned int)(r >> 32);
        #pragma unroll
        for (int k = 0; k < 4; ++k) {
            acc[k]     = fmaf(nrm, (float)((lo >> (8 * k)) & 0xffu) - 128.f, acc[k]);
            acc[k + 4] = fmaf(nrm, (float)((hi >> (8 * k)) & 0xffu) - 128.f, acc[k + 4]);
        }
    }
    // reduce across the 4 slots (allreduce -> every lane has full acc)
    #pragma unroll
    for (int k = 0; k < 8; ++k) {
        acc[k] += __shfl_xor(acc[k], 16);
        acc[k] += __shfl_xor(acc[k], 32);
    }
    // activation sign bits: feature f = fl*8 + k
    unsigned int m8 = 0;
    #pragma unroll
    for (int k = 0; k < 8; ++k) {
        int f = fl * 8 + k;
        float v = alphaS[f] * acc[k] + bias[f];
        if (v < 0.f) m8 |= (1u << k);
    }
    // assemble 128-bit sign vector: word q=k>>2, bit (fl + 16*(k&3))
    unsigned long long x0 = 0, x1 = 0;
    #pragma unroll
    for (int k = 0; k < 4; ++k) {
        unsigned long long bk = __ballot((m8 >> k) & 1u);
        x0 |= (bk & 0xffffULL) << (16 * k);
    }
    #pragma unroll
    for (int k = 4; k < 8; ++k) {
        unsigned long long bk = __ballot((m8 >> k) & 1u);
        x1 |= (bk & 0xffffULL) << (16 * (k - 4));
    }
    if (OUTC == 128) {
        unsigned int pack = 0;
        #pragma unroll
        for (int t2 = 0; t2 < 2; ++t2) {
            int j = 2 * lane + t2;
            int dd = __popcll(x0 ^ wsm[j * 2]) + __popcll(x1 ^ wsm[j * 2 + 1]);
            int S = HD - 2 * dd;  // even, [-128,128]
            pack |= ((unsigned int)((S >> 1) + 128) & 0xffu) << (8 * t2);
        }
        *(unsigned short*)(Sout + (size_t)d * HD + 2 * lane) = (unsigned short)pack;
    } else {
        int p8 = 128;  // biased zero padding
        if (lane < OUTC) {
            int dd = __popcll(x0 ^ wsm[lane * 2]) + __popcll(x1 ^ wsm[lane * 2 + 1]);
            p8 = ((HD - 2 * dd) >> 1) + 128;
        }
        Sout[(size_t)d * S2_STRIDE + lane] = (unsigned char)p8;
    }
}

// ---------------- final agg + log_softmax ----------------
// wave = 1 dst; 4 slots x 16 lanes; lane loads 4B (features fl*4..fl*4+3); batched 2.
__global__ __launch_bounds__(256) void k_agg_out(const unsigned char* __restrict__ S2, // [N][64]
                                                 const int* __restrict__ row_ptr,
                                                 const long long* __restrict__ cs,
                                                 const float* __restrict__ dinv,
                                                 const float* __restrict__ alphaS2,
                                                 const float* __restrict__ b2,
                                                 float* __restrict__ out, int N) {
    int tid = threadIdx.x, lane = tid & 63;
    int d = blockIdx.x * 4 + (tid >> 6);
    if (d >= N) return;
    int sub = lane >> 4;
    int fl  = lane & 15;
    float acc[4] = {0.f, 0.f, 0.f, 0.f};
    if (sub == 0) {            // self loop
        float dv = dinv[d];
        float nrm = dv * dv;
        unsigned int r4 = *(const unsigned int*)(S2 + (size_t)d * S2_STRIDE + fl * 4);
        #pragma unroll
        for (int k = 0; k < 4; ++k)
            acc[k] = fmaf(nrm, (float)((r4 >> (8 * k)) & 0xffu) - 128.f, acc[k]);
    }
    int e0 = row_ptr[d], e1 = row_ptr[d + 1];
    int e = e0 + sub;
    for (; e + 4 < e1; e += 8) {
        long long pa = cs[e];
        long long pb = cs[e + 4];
        int sa = (int)(unsigned int)pa;
        int sb = (int)(unsigned int)pb;
        unsigned int ra = *(const unsigned int*)(S2 + (size_t)sa * S2_STRIDE + fl * 4);
        unsigned int rb = *(const unsigned int*)(S2 + (size_t)sb * S2_STRIDE + fl * 4);
        float na = __int_as_float((int)(pa >> 32));
        float nb = __int_as_float((int)(pb >> 32));
        #pragma unroll
        for (int k = 0; k < 4; ++k) {
            acc[k] = fmaf(na, (float)((ra >> (8 * k)) & 0xffu) - 128.f, acc[k]);
            acc[k] = fmaf(nb, (float)((rb >> (8 * k)) & 0xffu) - 128.f, acc[k]);
        }
    }
    if (e < e1) {
        long long p = cs[e];
        int s = (int)(unsigned int)p;
        float nrm = __int_as_float((int)(p >> 32));
        unsigned int r4 = *(const unsigned int*)(S2 + (size_t)s * S2_STRIDE + fl * 4);
        #pragma unroll
        for (int k = 0; k < 4; ++k)
            acc[k] = fmaf(nrm, (float)((r4 >> (8 * k)) & 0xffu) - 128.f, acc[k]);
    }
    #pragma unroll
    for (int k = 0; k < 4; ++k) {
        acc[k] += __shfl_xor(acc[k], 16);
        acc[k] += __shfl_xor(acc[k], 32);
    }
    float h[4];
    float mymax = -INFINITY;
    #pragma unroll
    for (int k = 0; k < 4; ++k) {
        int f = fl * 4 + k;
        h[k] = (f < OUT_DIM) ? (alphaS2[f] * acc[k] + b2[f]) : -INFINITY;
        mymax = fmaxf(mymax, h[k]);
    }
    #pragma unroll
    for (int off = 1; off < 16; off <<= 1) mymax = fmaxf(mymax, __shfl_xor(mymax, off));
    float s4 = 0.f;
    #pragma unroll
    for (int k = 0; k < 4; ++k) {
        if (fl * 4 + k < OUT_DIM) s4 += expf(h[k] - mymax);
    }
    #pragma unroll
    for (int off = 1; off < 16; off <<= 1) s4 += __shfl_xor(s4, off);
    float lse = mymax + logf(s4);
    if (sub == 0 && fl < OUT_DIM / 4) {
        float4 o;
        o.x = h[0] - lse; o.y = h[1] - lse; o.z = h[2] - lse; o.w = h[3] - lse;
        *(float4*)(out + (size_t)d * OUT_DIM + fl * 4) = o;
    }
}

// ---------------- launcher ----------------
extern "C" void kernel_launch(void* const* d_in, const int* in_sizes, int n_in,
                              void* d_out, int out_size, void* d_ws, size_t ws_size,
                              hipStream_t stream) {
    const float* x  = (const float*)d_in[0];
    const int*   ei = (const int*)d_in[1];
    const float* W0 = (const float*)d_in[2];
    const float* b0 = (const float*)d_in[3];
    const float* W1 = (const float*)d_in[4];
    const float* b1 = (const float*)d_in[5];
    const float* W2 = (const float*)d_in[6];
    const float* b2 = (const float*)d_in[7];
    float* out = (float*)d_out;

    int N = in_sizes[0] / IN_DIM;
    int E = in_sizes[1] / 2;

    char* ws = (char*)d_ws;
    size_t off = 0;
    auto alloc = [&](size_t bytes) -> void* {
        off = (off + 255) & ~(size_t)255;
        void* p = (void*)(ws + off);
        off += bytes;
        return p;
    };
    float* muacc  = (float*)alloc(256 * 4);
    int*   deg    = (int*)alloc((size_t)N * 4);
    float* dinv   = (float*)alloc((size_t)N * 4);
    int*   rowp   = (int*)alloc(((size_t)N + 1) * 4);
    int*   bp     = (int*)alloc(512 * 4);
    int*   bps    = (int*)alloc(512 * 4);
    int*   rank   = (int*)alloc((size_t)E * 4);
    long long* cs = (long long*)alloc((size_t)E * 8);
    unsigned char* S0 = (unsigned char*)alloc((size_t)N * HD);
    unsigned char* S1 = (unsigned char*)alloc((size_t)N * HD);
    unsigned char* S2 = (unsigned char*)alloc((size_t)N * S2_STRIDE);
    unsigned long long* W0p = (unsigned long long*)alloc(128 * 4 * 8);
    unsigned long long* W1p = (unsigned long long*)alloc(128 * 2 * 8);
    unsigned long long* W2p = (unsigned long long*)alloc(40 * 2 * 8);
    float* aS0 = (float*)alloc(128 * 4);
    float* aS1 = (float*)alloc(128 * 4);
    float* aS2 = (float*)alloc(40 * 4);

    int nb256 = (N + 255) / 256;
    int ebl = (E + 255) / 256;
    float inv_n = 1.0f / (float)N;

    k_init<<<dim3(nb256), dim3(256), 0, stream>>>(deg, muacc, N);
    k_fuse1<<<dim3(NB_CS + ebl + 74), dim3(256), 0, stream>>>(
        x, N, muacc, ei, E, deg, rank, ebl, W0, W1, W2, W0p, W1p, W2p, aS0, aS1, aS2);
    k_bp<<<dim3(nb256), dim3(256), 0, stream>>>(deg, N, bp);
    k_scanbp<<<dim3(1), dim3(512), 0, stream>>>(bp, nb256, bps);
    k_rowptr<<<dim3(nb256), dim3(256), 0, stream>>>(deg, bps, N, E, rowp, dinv);

    int nb4 = (N + 3) / 4;
    k_fuse2<<<dim3(ebl + nb4), dim3(256), 0, stream>>>(
        ei, E, dinv, rowp, rank, cs, ebl, x, muacc, inv_n, W0p, S0, N);
    k_agg_mm<128><<<dim3(nb4), dim3(256), 0, stream>>>(S0, rowp, cs, dinv, aS0, b0, W1p, S1, N);
    k_agg_mm<40><<<dim3(nb4), dim3(256), 0, stream>>>(S1, rowp, cs, dinv, aS1, b1, W2p, S2, N);
    k_agg_out<<<dim3(nb4), dim3(256), 0, stream>>>(S2, rowp, cs, dinv, aS2, b2, out, N);
    (void)out_size; (void)ws_size; (void)n_in;
}